// Round 1
// baseline (257.668 us; speedup 1.0000x reference)
//
#include <hip/hip_runtime.h>
#include <hip/hip_bf16.h>

#define N_NODES 4096
#define IN_DIM  256
#define OUT_DIM 128
#define EDGE_DIM 64
#define N_SAMPLE 128

__device__ __forceinline__ float wsum64(float v) {
#pragma unroll
  for (int off = 32; off; off >>= 1) v += __shfl_xor(v, off, 64);
  return v;
}
__device__ __forceinline__ float wmax64(float v) {
#pragma unroll
  for (int off = 32; off; off >>= 1) v = fmaxf(v, __shfl_xor(v, off, 64));
  return v;
}

// ---------------- x = features @ W  (4096x256 @ 256x128) ----------------
// 8 rows per block, 128 threads; features rows staged in LDS, W reads coalesced.
__global__ void __launch_bounds__(128) gemm_x_kernel(const float* __restrict__ feat,
                                                     const float* __restrict__ W,
                                                     float* __restrict__ x) {
  const int t  = threadIdx.x;
  const int v0 = blockIdx.x * 8;
  __shared__ float f[8][IN_DIM];
  float* fflat = &f[0][0];
  for (int idx = t; idx < 8 * IN_DIM; idx += 128)
    fflat[idx] = feat[v0 * IN_DIM + idx];
  __syncthreads();
  float acc[8] = {0.f, 0.f, 0.f, 0.f, 0.f, 0.f, 0.f, 0.f};
  for (int i = 0; i < IN_DIM; i += 4) {
    const float w0 = W[(i + 0) * OUT_DIM + t];
    const float w1 = W[(i + 1) * OUT_DIM + t];
    const float w2 = W[(i + 2) * OUT_DIM + t];
    const float w3 = W[(i + 3) * OUT_DIM + t];
#pragma unroll
    for (int r = 0; r < 8; ++r) {
      const float4 fv = *reinterpret_cast<const float4*>(&f[r][i]);
      acc[r] += fv.x * w0 + fv.y * w1 + fv.z * w2 + fv.w * w3;
    }
  }
#pragma unroll
  for (int r = 0; r < 8; ++r) x[(v0 + r) * OUT_DIM + t] = acc[r];
}

// ---------------- s1[v] = x[v].a1, s2[v] = x[v].a2 ----------------
__global__ void __launch_bounds__(64) s12_kernel(const float* __restrict__ x,
                                                 const float* __restrict__ a,
                                                 float* __restrict__ s1,
                                                 float* __restrict__ s2) {
  const int v = blockIdx.x, l = threadIdx.x;
  const float x0 = x[v * OUT_DIM + l], x1 = x[v * OUT_DIM + 64 + l];
  float c1 = x0 * a[l] + x1 * a[64 + l];
  float c2 = x0 * a[OUT_DIM + l] + x1 * a[OUT_DIM + 64 + l];
  c1 = wsum64(c1);
  c2 = wsum64(c2);
  if (l == 0) { s1[v] = c1; s2[v] = c2; }
}

// ---------------- s3[r] = emb[r].a3  (rows = n+1) ----------------
__global__ void __launch_bounds__(256) s3_kernel(const float* __restrict__ emb,
                                                 const float* __restrict__ a,
                                                 float* __restrict__ s3, int rows) {
  const int w = threadIdx.x >> 6, l = threadIdx.x & 63;
  const int r = blockIdx.x * 4 + w;
  if (r >= rows) return;
  float c = emb[r * EDGE_DIM + l] * a[2 * OUT_DIM + l];
  c = wsum64(c);
  if (l == 0) s3[r] = c;
}

// ---------------- attention + aggregate + ELU ----------------
// one block (128 threads, 2 waves) per node
__global__ void __launch_bounds__(128) attn_kernel(const float* __restrict__ x,
                                                   const float* __restrict__ s1,
                                                   const float* __restrict__ s2,
                                                   const float* __restrict__ s3,
                                                   const int* __restrict__ neigh,
                                                   const int* __restrict__ eidx,
                                                   float* __restrict__ out) {
  const int v = blockIdx.x;
  const int t = threadIdx.x;              // 0..127
  __shared__ float att[N_SAMPLE];
  __shared__ int   us[N_SAMPLE];
  __shared__ float red[4];

  const int u   = neigh[v * N_SAMPLE + t];
  const int eid = eidx[v * N_NODES + u];
  float e = s1[v] + s2[u] + s3[eid];
  e = e > 0.f ? e : 0.2f * e;             // leaky_relu alpha=0.2
  us[t] = u;

  const int wid = t >> 6, l = t & 63;
  float m = wmax64(e);
  if (l == 0) red[wid] = m;
  __syncthreads();
  m = fmaxf(red[0], red[1]);
  const float p = __expf(e - m);
  float ssum = wsum64(p);
  if (l == 0) red[2 + wid] = ssum;
  att[t] = p;
  __syncthreads();
  const float inv = 1.0f / (red[2] + red[3]);

  float h = 0.f;
#pragma unroll 8
  for (int s = 0; s < N_SAMPLE; ++s)
    h += att[s] * x[us[s] * OUT_DIM + t];
  h *= inv;

  const float o = h + x[v * OUT_DIM + t];
  out[v * OUT_DIM + t] = o > 0.f ? o : expm1f(o);   // ELU
}

// ---------------- edge embedding update ----------------
// 4 edges per block, 64 threads; thread = (edge g, 4 cols c..c+3)
__global__ void __launch_bounds__(64) edge_kernel(const float* __restrict__ out,
                                                  const float* __restrict__ emb,
                                                  const int* __restrict__ eidx,
                                                  const int* __restrict__ tu,
                                                  const float* __restrict__ W2,
                                                  const float* __restrict__ W3,
                                                  const float* __restrict__ Bv,
                                                  float* __restrict__ emb_new, int n) {
  const int t  = threadIdx.x;
  const int g  = t >> 4;
  const int c  = (t & 15) << 2;
  const int k0 = blockIdx.x * 4;
  __shared__ float o[4][132];   // +4 pad: groups land on distinct banks
  __shared__ float em[4][68];
#pragma unroll
  for (int e = 0; e < 4; ++e) {
    const int k = k0 + e;
    if (k < n) {
      const int i = tu[2 * k], j = tu[2 * k + 1];
      o[e][t]      = out[i * OUT_DIM + t]      + out[j * OUT_DIM + t];
      o[e][t + 64] = out[i * OUT_DIM + 64 + t] + out[j * OUT_DIM + 64 + t];
      const int id = eidx[i * N_NODES + j];
      em[e][t] = emb[id * EDGE_DIM + t];
    }
  }
  __syncthreads();
  const int k = k0 + g;
  const float4 b4 = *reinterpret_cast<const float4*>(&Bv[c]);
  float ax = b4.x, ay = b4.y, az = b4.z, aw = b4.w;
  for (int d = 0; d < OUT_DIM; ++d) {
    const float4 w = *reinterpret_cast<const float4*>(&W2[d * EDGE_DIM + c]);
    const float od = o[g][d];
    ax += od * w.x; ay += od * w.y; az += od * w.z; aw += od * w.w;
  }
  for (int d = 0; d < EDGE_DIM; ++d) {
    const float4 w = *reinterpret_cast<const float4*>(&W3[d * EDGE_DIM + c]);
    const float ed = em[g][d];
    ax += ed * w.x; ay += ed * w.y; az += ed * w.z; aw += ed * w.w;
  }
  if (k < n) {
    const float4 ek = *reinterpret_cast<const float4*>(&emb[(k + 1) * EDGE_DIM + c]);
    float4 r;
    r.x = fmaxf(ax * ek.x, 0.f);
    r.y = fmaxf(ay * ek.y, 0.f);
    r.z = fmaxf(az * ek.z, 0.f);
    r.w = fmaxf(aw * ek.w, 0.f);
    *reinterpret_cast<float4*>(&emb_new[(k + 1) * EDGE_DIM + c]) = r;
  }
  // row 0 of emb_new = relu(B * emb[0])
  if (blockIdx.x == 0 && t < 16) {
    const int c0 = t * 4;
    const float4 b0 = *reinterpret_cast<const float4*>(&Bv[c0]);
    const float4 e0 = *reinterpret_cast<const float4*>(&emb[c0]);
    float4 r;
    r.x = fmaxf(b0.x * e0.x, 0.f);
    r.y = fmaxf(b0.y * e0.y, 0.f);
    r.z = fmaxf(b0.z * e0.z, 0.f);
    r.w = fmaxf(b0.w * e0.w, 0.f);
    *reinterpret_cast<float4*>(&emb_new[c0]) = r;
  }
}

extern "C" void kernel_launch(void* const* d_in, const int* in_sizes, int n_in,
                              void* d_out, int out_size, void* d_ws, size_t ws_size,
                              hipStream_t stream) {
  const float* feat = (const float*)d_in[0];
  const int*   eidx = (const int*)d_in[1];
  const int*   neigh = (const int*)d_in[2];
  const int*   tu   = (const int*)d_in[3];
  const float* emb  = (const float*)d_in[4];
  const float* W    = (const float*)d_in[5];
  const float* W2   = (const float*)d_in[6];
  const float* W3   = (const float*)d_in[7];
  const float* Bv   = (const float*)d_in[8];
  const float* a    = (const float*)d_in[9];
  const int n    = in_sizes[3] / 2;           // number of edges to update
  const int rows = in_sizes[4] / EDGE_DIM;    // n + 1 emb rows

  float* x  = (float*)d_ws;                   // 4096*128
  float* s1 = x + N_NODES * OUT_DIM;          // 4096
  float* s2 = s1 + N_NODES;                   // 4096
  float* s3 = s2 + N_NODES;                   // rows

  float* out_nodes = (float*)d_out;                     // 4096*128
  float* emb_new   = out_nodes + N_NODES * OUT_DIM;     // rows*64

  hipLaunchKernelGGL(gemm_x_kernel, dim3(N_NODES / 8), dim3(128), 0, stream, feat, W, x);
  hipLaunchKernelGGL(s12_kernel, dim3(N_NODES), dim3(64), 0, stream, x, a, s1, s2);
  hipLaunchKernelGGL(s3_kernel, dim3((rows + 3) / 4), dim3(256), 0, stream, emb, a, s3, rows);
  hipLaunchKernelGGL(attn_kernel, dim3(N_NODES), dim3(128), 0, stream,
                     x, s1, s2, s3, neigh, eidx, out_nodes);
  hipLaunchKernelGGL(edge_kernel, dim3((n + 3) / 4), dim3(64), 0, stream,
                     out_nodes, emb, eidx, tu, W2, W3, Bv, emb_new, n);
}

// Round 2
// 207.487 us; speedup vs baseline: 1.2419x; 1.2419x over previous
//
#include <hip/hip_runtime.h>
#include <hip/hip_bf16.h>

#define N_NODES 4096
#define IN_DIM  256
#define OUT_DIM 128
#define EDGE_DIM 64
#define N_SAMPLE 128

__device__ __forceinline__ float wsum64(float v) {
#pragma unroll
  for (int off = 32; off; off >>= 1) v += __shfl_xor(v, off, 64);
  return v;
}
__device__ __forceinline__ float wmax64(float v) {
#pragma unroll
  for (int off = 32; off; off >>= 1) v = fmaxf(v, __shfl_xor(v, off, 64));
  return v;
}

// ---------------- x = features @ W  (4096x256 @ 256x128) ----------------
__global__ void __launch_bounds__(128) gemm_x_kernel(const float* __restrict__ feat,
                                                     const float* __restrict__ W,
                                                     float* __restrict__ x) {
  const int t  = threadIdx.x;
  const int v0 = blockIdx.x * 8;
  __shared__ float f[8][IN_DIM];
  float* fflat = &f[0][0];
  for (int idx = t; idx < 8 * IN_DIM; idx += 128)
    fflat[idx] = feat[v0 * IN_DIM + idx];
  __syncthreads();
  float acc[8] = {0.f, 0.f, 0.f, 0.f, 0.f, 0.f, 0.f, 0.f};
  for (int i = 0; i < IN_DIM; i += 4) {
    const float w0 = W[(i + 0) * OUT_DIM + t];
    const float w1 = W[(i + 1) * OUT_DIM + t];
    const float w2 = W[(i + 2) * OUT_DIM + t];
    const float w3 = W[(i + 3) * OUT_DIM + t];
#pragma unroll
    for (int r = 0; r < 8; ++r) {
      const float4 fv = *reinterpret_cast<const float4*>(&f[r][i]);
      acc[r] += fv.x * w0 + fv.y * w1 + fv.z * w2 + fv.w * w3;
    }
  }
#pragma unroll
  for (int r = 0; r < 8; ++r) x[(v0 + r) * OUT_DIM + t] = acc[r];
}

// ---------------- s1[v] = x[v].a1, s2[v] = x[v].a2 ----------------
__global__ void __launch_bounds__(64) s12_kernel(const float* __restrict__ x,
                                                 const float* __restrict__ a,
                                                 float* __restrict__ s1,
                                                 float* __restrict__ s2) {
  const int v = blockIdx.x, l = threadIdx.x;
  const float x0 = x[v * OUT_DIM + l], x1 = x[v * OUT_DIM + 64 + l];
  float c1 = x0 * a[l] + x1 * a[64 + l];
  float c2 = x0 * a[OUT_DIM + l] + x1 * a[OUT_DIM + 64 + l];
  c1 = wsum64(c1);
  c2 = wsum64(c2);
  if (l == 0) { s1[v] = c1; s2[v] = c2; }
}

// ---------------- s3[r] = emb[r].a3  (rows = n+1) ----------------
__global__ void __launch_bounds__(256) s3_kernel(const float* __restrict__ emb,
                                                 const float* __restrict__ a,
                                                 float* __restrict__ s3, int rows) {
  const int w = threadIdx.x >> 6, l = threadIdx.x & 63;
  const int r = blockIdx.x * 4 + w;
  if (r >= rows) return;
  float c = emb[r * EDGE_DIM + l] * a[2 * OUT_DIM + l];
  c = wsum64(c);
  if (l == 0) s3[r] = c;
}

// ---------------- attention + aggregate + ELU ----------------
__global__ void __launch_bounds__(128) attn_kernel(const float* __restrict__ x,
                                                   const float* __restrict__ s1,
                                                   const float* __restrict__ s2,
                                                   const float* __restrict__ s3,
                                                   const int* __restrict__ neigh,
                                                   const int* __restrict__ eidx,
                                                   float* __restrict__ out) {
  const int v = blockIdx.x;
  const int t = threadIdx.x;              // 0..127
  __shared__ float att[N_SAMPLE];
  __shared__ int   us[N_SAMPLE];
  __shared__ float red[4];

  const int u   = neigh[v * N_SAMPLE + t];
  const int eid = eidx[v * N_NODES + u];
  float e = s1[v] + s2[u] + s3[eid];
  e = e > 0.f ? e : 0.2f * e;             // leaky_relu alpha=0.2
  us[t] = u;

  const int wid = t >> 6, l = t & 63;
  float m = wmax64(e);
  if (l == 0) red[wid] = m;
  __syncthreads();
  m = fmaxf(red[0], red[1]);
  const float p = __expf(e - m);
  float ssum = wsum64(p);
  if (l == 0) red[2 + wid] = ssum;
  att[t] = p;
  __syncthreads();
  const float inv = 1.0f / (red[2] + red[3]);

  float h = 0.f;
#pragma unroll 8
  for (int s = 0; s < N_SAMPLE; ++s)
    h += att[s] * x[us[s] * OUT_DIM + t];
  h *= inv;

  const float o = h + x[v * OUT_DIM + t];
  out[v * OUT_DIM + t] = o > 0.f ? o : expm1f(o);   // ELU
}

// ---------------- edge embedding update: tiled GEMM ----------------
// C[64 edges][64 cols] = relu((Ain[64][192] @ Wcat[192][64] + B) * emb[k+1])
// 256 threads, per-thread 4x4 microtile. Ain staged in LDS (pad 196 -> <=2-way
// conflicts, free). W2/W3 read from global (L2-hot, fully unrolled k-groups).
#define TE 64
__global__ void __launch_bounds__(256) edge_gemm_kernel(const float* __restrict__ out,
                                                        const float* __restrict__ emb,
                                                        const int* __restrict__ eidx,
                                                        const int* __restrict__ tu,
                                                        const float* __restrict__ W2,
                                                        const float* __restrict__ W3,
                                                        const float* __restrict__ Bv,
                                                        float* __restrict__ emb_new, int n) {
  const int t  = threadIdx.x;
  const int k0 = blockIdx.x * TE;
  __shared__ float Ain[TE][196];   // [edge][k], 192 + 4 pad

  // ---- stage Ain: 4 threads per edge ----
  {
    const int e  = t >> 2, q = t & 3;
    const int ke = k0 + e;
    if (ke < n) {
      const int i = tu[2 * ke], j = tu[2 * ke + 1];
#pragma unroll
      for (int kk = 0; kk < 32; kk += 4) {
        const int k = q * 32 + kk;
        const float4 oi = *reinterpret_cast<const float4*>(&out[i * OUT_DIM + k]);
        const float4 oj = *reinterpret_cast<const float4*>(&out[j * OUT_DIM + k]);
        float4 r; r.x = oi.x + oj.x; r.y = oi.y + oj.y; r.z = oi.z + oj.z; r.w = oi.w + oj.w;
        *reinterpret_cast<float4*>(&Ain[e][k]) = r;
      }
      const int id = eidx[i * N_NODES + j];
#pragma unroll
      for (int kk = 0; kk < 16; kk += 4) {
        const int k = q * 16 + kk;
        *reinterpret_cast<float4*>(&Ain[e][128 + k]) =
            *reinterpret_cast<const float4*>(&emb[id * EDGE_DIM + k]);
      }
    }
  }
  __syncthreads();

  // ---- compute 4x4 microtile ----
  const int e0 = (t >> 4) * 4;         // 4 edges
  const int c0 = (t & 15) * 4;         // 4 cols
  const float4 b4 = *reinterpret_cast<const float4*>(&Bv[c0]);
  float4 acc[4];
#pragma unroll
  for (int m = 0; m < 4; ++m) acc[m] = b4;

#pragma unroll 2
  for (int k = 0; k < 128; k += 4) {   // W2 part
    float4 a[4];
#pragma unroll
    for (int m = 0; m < 4; ++m) a[m] = *reinterpret_cast<const float4*>(&Ain[e0 + m][k]);
#pragma unroll
    for (int kk = 0; kk < 4; ++kk) {
      const float4 w = *reinterpret_cast<const float4*>(&W2[(k + kk) * EDGE_DIM + c0]);
#pragma unroll
      for (int m = 0; m < 4; ++m) {
        const float av = reinterpret_cast<const float*>(&a[m])[kk];
        acc[m].x += av * w.x; acc[m].y += av * w.y; acc[m].z += av * w.z; acc[m].w += av * w.w;
      }
    }
  }
#pragma unroll 2
  for (int k = 0; k < 64; k += 4) {    // W3 part
    float4 a[4];
#pragma unroll
    for (int m = 0; m < 4; ++m) a[m] = *reinterpret_cast<const float4*>(&Ain[e0 + m][128 + k]);
#pragma unroll
    for (int kk = 0; kk < 4; ++kk) {
      const float4 w = *reinterpret_cast<const float4*>(&W3[(k + kk) * EDGE_DIM + c0]);
#pragma unroll
      for (int m = 0; m < 4; ++m) {
        const float av = reinterpret_cast<const float*>(&a[m])[kk];
        acc[m].x += av * w.x; acc[m].y += av * w.y; acc[m].z += av * w.z; acc[m].w += av * w.w;
      }
    }
  }

  // ---- epilogue: emb_new[edge+1] = relu(acc * emb[edge+1]) ----
#pragma unroll
  for (int m = 0; m < 4; ++m) {
    const int ke = k0 + e0 + m;
    if (ke < n) {
      const float4 ek = *reinterpret_cast<const float4*>(&emb[(ke + 1) * EDGE_DIM + c0]);
      float4 r;
      r.x = fmaxf(acc[m].x * ek.x, 0.f);
      r.y = fmaxf(acc[m].y * ek.y, 0.f);
      r.z = fmaxf(acc[m].z * ek.z, 0.f);
      r.w = fmaxf(acc[m].w * ek.w, 0.f);
      *reinterpret_cast<float4*>(&emb_new[(ke + 1) * EDGE_DIM + c0]) = r;
    }
  }
  // row 0 of emb_new = relu(B * emb[0])
  if (blockIdx.x == 0 && t < 16) {
    const int cc = t * 4;
    const float4 b0 = *reinterpret_cast<const float4*>(&Bv[cc]);
    const float4 e0v = *reinterpret_cast<const float4*>(&emb[cc]);
    float4 r;
    r.x = fmaxf(b0.x * e0v.x, 0.f);
    r.y = fmaxf(b0.y * e0v.y, 0.f);
    r.z = fmaxf(b0.z * e0v.z, 0.f);
    r.w = fmaxf(b0.w * e0v.w, 0.f);
    *reinterpret_cast<float4*>(&emb_new[cc]) = r;
  }
}

extern "C" void kernel_launch(void* const* d_in, const int* in_sizes, int n_in,
                              void* d_out, int out_size, void* d_ws, size_t ws_size,
                              hipStream_t stream) {
  const float* feat  = (const float*)d_in[0];
  const int*   eidx  = (const int*)d_in[1];
  const int*   neigh = (const int*)d_in[2];
  const int*   tu    = (const int*)d_in[3];
  const float* emb   = (const float*)d_in[4];
  const float* W     = (const float*)d_in[5];
  const float* W2    = (const float*)d_in[6];
  const float* W3    = (const float*)d_in[7];
  const float* Bv    = (const float*)d_in[8];
  const float* a     = (const float*)d_in[9];
  const int n    = in_sizes[3] / 2;           // edges to update
  const int rows = in_sizes[4] / EDGE_DIM;    // n + 1 emb rows

  float* x  = (float*)d_ws;                   // 4096*128
  float* s1 = x + N_NODES * OUT_DIM;
  float* s2 = s1 + N_NODES;
  float* s3 = s2 + N_NODES;

  float* out_nodes = (float*)d_out;
  float* emb_new   = out_nodes + N_NODES * OUT_DIM;

  hipLaunchKernelGGL(gemm_x_kernel, dim3(N_NODES / 8), dim3(128), 0, stream, feat, W, x);
  hipLaunchKernelGGL(s12_kernel, dim3(N_NODES), dim3(64), 0, stream, x, a, s1, s2);
  hipLaunchKernelGGL(s3_kernel, dim3((rows + 3) / 4), dim3(256), 0, stream, emb, a, s3, rows);
  hipLaunchKernelGGL(attn_kernel, dim3(N_NODES), dim3(128), 0, stream,
                     x, s1, s2, s3, neigh, eidx, out_nodes);
  hipLaunchKernelGGL(edge_gemm_kernel, dim3((n + TE - 1) / TE), dim3(256), 0, stream,
                     out_nodes, emb, eidx, tu, W2, W3, Bv, emb_new, n);
}

// Round 3
// 198.013 us; speedup vs baseline: 1.3013x; 1.0478x over previous
//
#include <hip/hip_runtime.h>
#include <hip/hip_bf16.h>

#define N_NODES 4096
#define IN_DIM  256
#define OUT_DIM 128
#define EDGE_DIM 64
#define N_SAMPLE 128

__device__ __forceinline__ float wsum64(float v) {
#pragma unroll
  for (int off = 32; off; off >>= 1) v += __shfl_xor(v, off, 64);
  return v;
}
__device__ __forceinline__ float wmax64(float v) {
#pragma unroll
  for (int off = 32; off; off >>= 1) v = fmaxf(v, __shfl_xor(v, off, 64));
  return v;
}

// ---------------- x = features @ W  (4096x256 @ 256x128) ----------------
__global__ void __launch_bounds__(128) gemm_x_kernel(const float* __restrict__ feat,
                                                     const float* __restrict__ W,
                                                     float* __restrict__ x) {
  const int t  = threadIdx.x;
  const int v0 = blockIdx.x * 8;
  __shared__ float f[8][IN_DIM];
  float* fflat = &f[0][0];
  for (int idx = t; idx < 8 * IN_DIM; idx += 128)
    fflat[idx] = feat[v0 * IN_DIM + idx];
  __syncthreads();
  float acc[8] = {0.f, 0.f, 0.f, 0.f, 0.f, 0.f, 0.f, 0.f};
  for (int i = 0; i < IN_DIM; i += 4) {
    const float w0 = W[(i + 0) * OUT_DIM + t];
    const float w1 = W[(i + 1) * OUT_DIM + t];
    const float w2 = W[(i + 2) * OUT_DIM + t];
    const float w3 = W[(i + 3) * OUT_DIM + t];
#pragma unroll
    for (int r = 0; r < 8; ++r) {
      const float4 fv = *reinterpret_cast<const float4*>(&f[r][i]);
      acc[r] += fv.x * w0 + fv.y * w1 + fv.z * w2 + fv.w * w3;
    }
  }
#pragma unroll
  for (int r = 0; r < 8; ++r) x[(v0 + r) * OUT_DIM + t] = acc[r];
}

// ---------------- s1[v] = x[v].a1, s2[v] = x[v].a2 ----------------
__global__ void __launch_bounds__(64) s12_kernel(const float* __restrict__ x,
                                                 const float* __restrict__ a,
                                                 float* __restrict__ s1,
                                                 float* __restrict__ s2) {
  const int v = blockIdx.x, l = threadIdx.x;
  const float x0 = x[v * OUT_DIM + l], x1 = x[v * OUT_DIM + 64 + l];
  float c1 = x0 * a[l] + x1 * a[64 + l];
  float c2 = x0 * a[OUT_DIM + l] + x1 * a[OUT_DIM + 64 + l];
  c1 = wsum64(c1);
  c2 = wsum64(c2);
  if (l == 0) { s1[v] = c1; s2[v] = c2; }
}

// ---------------- s3[r] = emb[r].a3  (rows = n+1) ----------------
__global__ void __launch_bounds__(256) s3_kernel(const float* __restrict__ emb,
                                                 const float* __restrict__ a,
                                                 float* __restrict__ s3, int rows) {
  const int w = threadIdx.x >> 6, l = threadIdx.x & 63;
  const int r = blockIdx.x * 4 + w;
  if (r >= rows) return;
  float c = emb[r * EDGE_DIM + l] * a[2 * OUT_DIM + l];
  c = wsum64(c);
  if (l == 0) s3[r] = c;
}

// ---------------- attention + aggregate + ELU ----------------
// one block = ONE wave per node; each thread owns 2 output cols (float2).
__global__ void __launch_bounds__(64) attn_kernel(const float* __restrict__ x,
                                                  const float* __restrict__ s1,
                                                  const float* __restrict__ s2,
                                                  const float* __restrict__ s3,
                                                  const int* __restrict__ neigh,
                                                  const int* __restrict__ eidx,
                                                  float* __restrict__ out) {
  const int v = blockIdx.x;
  const int t = threadIdx.x;              // 0..63
  __shared__ float att[N_SAMPLE];
  __shared__ int   us[N_SAMPLE];

  const int u0 = neigh[v * N_SAMPLE + t];
  const int u1 = neigh[v * N_SAMPLE + 64 + t];
  us[t]      = u0;
  us[t + 64] = u1;
  const float s1v = s1[v];
  float e0 = s1v + s2[u0] + s3[eidx[v * N_NODES + u0]];
  float e1 = s1v + s2[u1] + s3[eidx[v * N_NODES + u1]];
  e0 = e0 > 0.f ? e0 : 0.2f * e0;
  e1 = e1 > 0.f ? e1 : 0.2f * e1;
  const float m = wmax64(fmaxf(e0, e1));
  const float p0 = __expf(e0 - m), p1 = __expf(e1 - m);
  const float inv = 1.0f / wsum64(p0 + p1);
  att[t]      = p0;
  att[t + 64] = p1;
  __syncthreads();

  float2 h = make_float2(0.f, 0.f);
#pragma unroll 8
  for (int s = 0; s < N_SAMPLE; ++s) {
    const float a = att[s];
    const float2 xv = *reinterpret_cast<const float2*>(&x[us[s] * OUT_DIM + 2 * t]);
    h.x += a * xv.x;
    h.y += a * xv.y;
  }
  const float2 xs = *reinterpret_cast<const float2*>(&x[v * OUT_DIM + 2 * t]);
  float ox = h.x * inv + xs.x;
  float oy = h.y * inv + xs.y;
  ox = ox > 0.f ? ox : expm1f(ox);
  oy = oy > 0.f ? oy : expm1f(oy);
  float2 r = make_float2(ox, oy);
  *reinterpret_cast<float2*>(&out[v * OUT_DIM + 2 * t]) = r;
}

// ---------------- Y = out @ W2  (4096x128 @ 128x64) ----------------
__global__ void __launch_bounds__(256) y_kernel(const float* __restrict__ out,
                                                const float* __restrict__ W2,
                                                float* __restrict__ Y) {
  const int t  = threadIdx.x;
  const int r0 = blockIdx.x * 16;
  __shared__ float o[16][132];   // pad -> conflict-free broadcast groups
  for (int idx = t; idx < 16 * OUT_DIM; idx += 256)
    o[idx >> 7][idx & 127] = out[r0 * OUT_DIM + idx];
  __syncthreads();
  const int r  = t >> 4;
  const int c0 = (t & 15) * 4;
  float4 acc = make_float4(0.f, 0.f, 0.f, 0.f);
  for (int k = 0; k < OUT_DIM; k += 4) {
#pragma unroll
    for (int kk = 0; kk < 4; ++kk) {
      const float av = o[r][k + kk];
      const float4 w = *reinterpret_cast<const float4*>(&W2[(k + kk) * EDGE_DIM + c0]);
      acc.x += av * w.x; acc.y += av * w.y; acc.z += av * w.z; acc.w += av * w.w;
    }
  }
  *reinterpret_cast<float4*>(&Y[(r0 + r) * EDGE_DIM + c0]) = acc;
}

// ---------------- fused edge update ----------------
// emb_new[k+1] = relu((emb[eid[k]] @ W3 + Y[i]+Y[j] + B) * emb[k+1])
// 64 edges/block, 256 threads, 4x4 microtile on the K=64 GEMM.
#define TE 64
__global__ void __launch_bounds__(256) edge_fused_kernel(const float* __restrict__ Y,
                                                         const float* __restrict__ emb,
                                                         const int* __restrict__ eidx,
                                                         const int* __restrict__ tu,
                                                         const float* __restrict__ W3,
                                                         const float* __restrict__ Bv,
                                                         float* __restrict__ emb_new, int n) {
  const int t  = threadIdx.x;
  const int k0 = blockIdx.x * TE;
  __shared__ float Ain[TE][68];    // emb[eid] rows, +4 pad
  __shared__ int   tus[2 * TE];

  if (t < 2 * TE) {
    const int idx = 2 * k0 + t;
    tus[t] = (idx < 2 * n) ? tu[idx] : 0;
  }
  {
    const int e  = t >> 2, q = t & 3;
    const int ke = k0 + e;
    if (ke < n) {
      const int i = tu[2 * ke], j = tu[2 * ke + 1];
      const int id = eidx[i * N_NODES + j];
#pragma unroll
      for (int kk = 0; kk < 16; kk += 4) {
        const int k = q * 16 + kk;
        *reinterpret_cast<float4*>(&Ain[e][k]) =
            *reinterpret_cast<const float4*>(&emb[id * EDGE_DIM + k]);
      }
    }
  }
  __syncthreads();

  const int e0 = (t >> 4) * 4;     // 4 edges
  const int c0 = (t & 15) * 4;     // 4 cols
  const float4 b4 = *reinterpret_cast<const float4*>(&Bv[c0]);
  float4 acc[4];
#pragma unroll
  for (int m = 0; m < 4; ++m) acc[m] = b4;

#pragma unroll 4
  for (int k = 0; k < EDGE_DIM; k += 4) {
    float4 a[4];
#pragma unroll
    for (int m = 0; m < 4; ++m) a[m] = *reinterpret_cast<const float4*>(&Ain[e0 + m][k]);
#pragma unroll
    for (int kk = 0; kk < 4; ++kk) {
      const float4 w = *reinterpret_cast<const float4*>(&W3[(k + kk) * EDGE_DIM + c0]);
#pragma unroll
      for (int m = 0; m < 4; ++m) {
        const float av = reinterpret_cast<const float*>(&a[m])[kk];
        acc[m].x += av * w.x; acc[m].y += av * w.y; acc[m].z += av * w.z; acc[m].w += av * w.w;
      }
    }
  }

#pragma unroll
  for (int m = 0; m < 4; ++m) {
    const int ke = k0 + e0 + m;
    if (ke < n) {
      const int i = tus[2 * (e0 + m)], j = tus[2 * (e0 + m) + 1];
      const float4 yi = *reinterpret_cast<const float4*>(&Y[i * EDGE_DIM + c0]);
      const float4 yj = *reinterpret_cast<const float4*>(&Y[j * EDGE_DIM + c0]);
      const float4 ek = *reinterpret_cast<const float4*>(&emb[(ke + 1) * EDGE_DIM + c0]);
      float4 r;
      r.x = fmaxf((acc[m].x + yi.x + yj.x) * ek.x, 0.f);
      r.y = fmaxf((acc[m].y + yi.y + yj.y) * ek.y, 0.f);
      r.z = fmaxf((acc[m].z + yi.z + yj.z) * ek.z, 0.f);
      r.w = fmaxf((acc[m].w + yi.w + yj.w) * ek.w, 0.f);
      *reinterpret_cast<float4*>(&emb_new[(ke + 1) * EDGE_DIM + c0]) = r;
    }
  }
  // row 0 of emb_new = relu(B * emb[0])
  if (blockIdx.x == 0 && t < 16) {
    const int cc = t * 4;
    const float4 b0 = *reinterpret_cast<const float4*>(&Bv[cc]);
    const float4 e0v = *reinterpret_cast<const float4*>(&emb[cc]);
    float4 r;
    r.x = fmaxf(b0.x * e0v.x, 0.f);
    r.y = fmaxf(b0.y * e0v.y, 0.f);
    r.z = fmaxf(b0.z * e0v.z, 0.f);
    r.w = fmaxf(b0.w * e0v.w, 0.f);
    *reinterpret_cast<float4*>(&emb_new[cc]) = r;
  }
}

extern "C" void kernel_launch(void* const* d_in, const int* in_sizes, int n_in,
                              void* d_out, int out_size, void* d_ws, size_t ws_size,
                              hipStream_t stream) {
  const float* feat  = (const float*)d_in[0];
  const int*   eidx  = (const int*)d_in[1];
  const int*   neigh = (const int*)d_in[2];
  const int*   tu    = (const int*)d_in[3];
  const float* emb   = (const float*)d_in[4];
  const float* W     = (const float*)d_in[5];
  const float* W2    = (const float*)d_in[6];
  const float* W3    = (const float*)d_in[7];
  const float* Bv    = (const float*)d_in[8];
  const float* a     = (const float*)d_in[9];
  const int n    = in_sizes[3] / 2;           // edges to update
  const int rows = in_sizes[4] / EDGE_DIM;    // n + 1 emb rows

  float* x  = (float*)d_ws;                   // 4096*128
  float* s1 = x + N_NODES * OUT_DIM;          // 4096
  float* s2 = s1 + N_NODES;                   // 4096
  float* s3 = s2 + N_NODES;                   // rows
  float* Y  = s3 + ((rows + 3) & ~3);         // 4096*64

  float* out_nodes = (float*)d_out;
  float* emb_new   = out_nodes + N_NODES * OUT_DIM;

  hipLaunchKernelGGL(gemm_x_kernel, dim3(N_NODES / 8), dim3(128), 0, stream, feat, W, x);
  hipLaunchKernelGGL(s12_kernel, dim3(N_NODES), dim3(64), 0, stream, x, a, s1, s2);
  hipLaunchKernelGGL(s3_kernel, dim3((rows + 3) / 4), dim3(256), 0, stream, emb, a, s3, rows);
  hipLaunchKernelGGL(attn_kernel, dim3(N_NODES), dim3(64), 0, stream,
                     x, s1, s2, s3, neigh, eidx, out_nodes);
  hipLaunchKernelGGL(y_kernel, dim3(N_NODES / 16), dim3(256), 0, stream,
                     out_nodes, W2, Y);
  hipLaunchKernelGGL(edge_fused_kernel, dim3((n + TE - 1) / TE), dim3(256), 0, stream,
                     Y, emb, eidx, tu, W3, Bv, emb_new, n);
}